// Round 1
// baseline (227.526 us; speedup 1.0000x reference)
//
#include <hip/hip_runtime.h>
#include <cmath>

typedef __attribute__((ext_vector_type(8))) short bf16x8;
typedef __attribute__((ext_vector_type(4))) float f32x4;

#define MFMA16(a,b,c) __builtin_amdgcn_mfma_f32_16x16x32_bf16((a),(b),(c),0,0,0)

#if __has_builtin(__builtin_amdgcn_exp2f)
#define EXP2F(x) __builtin_amdgcn_exp2f(x)
#else
#define EXP2F(x) exp2f(x)
#endif

// sqrt(128) * log2(e): reference divides by d**-0.5 (multiplies by sqrt(128));
// we fold it (and the exp->exp2 conversion) into theta at projection time.
#define KSCALE 16.3222312f

#define NB 4
#define CH 256
#define CI 128
#define NS 4096   // 64*64 spatial

__device__ __forceinline__ unsigned short f2bf(float f) {
    unsigned int u = __builtin_bit_cast(unsigned int, f);
    u += 0x7fffu + ((u >> 16) & 1u);           // RNE
    return (unsigned short)(u >> 16);
}
__device__ __forceinline__ unsigned int pk2(float lo, float hi) {
    return (unsigned int)f2bf(lo) | ((unsigned int)f2bf(hi) << 16);
}
__device__ __forceinline__ bf16x8 cvt8(float4 a, float4 b) {
    union { unsigned int u[4]; bf16x8 v; } r;
    r.u[0] = pk2(a.x, a.y); r.u[1] = pk2(a.z, a.w);
    r.u[2] = pk2(b.x, b.y); r.u[3] = pk2(b.z, b.w);
    return r.v;
}

// ---------------------------------------------------------------------------
// Kernel 1: projections.  grid(3 weights, 32 s-tiles, 4 batches), 256 thr.
// Block computes P[s0:s0+128][0:128] = x^T . W^T (+bias) for one weight.
// x^T tile staged in LDS as bf16 pairs packed in uint, 128 c at a time.
// Output: wi=0 -> gT[n][c][s] (transposed!), wi=1 -> theta (KSCALE-scaled),
// wi=2 -> phi.  All bf16, row = spatial, 128 channels contiguous (except gT).
// ---------------------------------------------------------------------------
__global__ __launch_bounds__(256, 2)
void proj_kernel(const float* __restrict__ x,
                 const float* __restrict__ w_g, const float* __restrict__ b_g,
                 const float* __restrict__ w_th, const float* __restrict__ b_th,
                 const float* __restrict__ w_ph, const float* __restrict__ b_ph,
                 unsigned short* __restrict__ theta,
                 unsigned short* __restrict__ phi,
                 unsigned short* __restrict__ gT) {
    const int tid  = threadIdx.x;
    const int wid  = tid >> 6;
    const int lane = tid & 63;
    const int quad = lane >> 4;
    const int l15  = lane & 15;
    const int wi    = blockIdx.x;      // 0=g, 1=theta, 2=phi
    const int stile = blockIdx.y;      // 0..31 (128 s each)
    const int n     = blockIdx.z;
    const int s0    = stile * 128;

    const float* xN = x + (size_t)n * CH * NS;
    const float* W  = (wi == 0) ? w_g : ((wi == 1) ? w_th : w_ph);
    const float* Bv = (wi == 0) ? b_g : ((wi == 1) ? b_th : b_ph);

    // [128 s][68 uint]  (64 used = 128 c as bf16 pairs, +4 pad -> 16B-aligned rows)
    __shared__ unsigned int xp[128 * 68];

    f32x4 acc[8][2];
#pragma unroll
    for (int ot = 0; ot < 8; ot++)
#pragma unroll
        for (int st = 0; st < 2; st++) acc[ot][st] = (f32x4){0.f, 0.f, 0.f, 0.f};

    for (int ch = 0; ch < 2; ch++) {       // two 128-channel halves
        __syncthreads();
        // stage: 2048 tasks (64 c-pairs x 32 float4-spans of s), 8 per thread
#pragma unroll
        for (int i = 0; i < 8; i++) {
            int t  = tid + 256 * i;
            int cp = t >> 5;               // 0..63
            int s4 = t & 31;               // 0..31
            int c0 = ch * 128 + cp * 2;
            const float* p0 = xN + (size_t)c0 * NS + s0 + s4 * 4;
            float4 a = *(const float4*)p0;
            float4 b = *(const float4*)(p0 + NS);
            xp[(s4 * 4 + 0) * 68 + cp] = pk2(a.x, b.x);
            xp[(s4 * 4 + 1) * 68 + cp] = pk2(a.y, b.y);
            xp[(s4 * 4 + 2) * 68 + cp] = pk2(a.z, b.z);
            xp[(s4 * 4 + 3) * 68 + cp] = pk2(a.w, b.w);
        }
        __syncthreads();
#pragma unroll
        for (int kc = 0; kc < 4; kc++) {
            bf16x8 af[2];
#pragma unroll
            for (int st = 0; st < 2; st++) {
                int row = wid * 32 + st * 16 + l15;
                af[st] = *(const bf16x8*)(&xp[row * 68 + kc * 16 + quad * 4]);
            }
#pragma unroll
            for (int ot = 0; ot < 8; ot++) {
                const float* wp = W + (size_t)(ot * 16 + l15) * CH + ch * 128 + kc * 32 + quad * 8;
                bf16x8 bf = cvt8(*(const float4*)wp, *(const float4*)(wp + 4));
#pragma unroll
                for (int st = 0; st < 2; st++)
                    acc[ot][st] = MFMA16(af[st], bf, acc[ot][st]);
            }
        }
    }
    // epilogue: D row = s (quad*4+r), col = o (l15)
#pragma unroll
    for (int ot = 0; ot < 8; ot++) {
        int o = ot * 16 + l15;
        float bias = Bv[o];
#pragma unroll
        for (int st = 0; st < 2; st++) {
#pragma unroll
            for (int r = 0; r < 4; r++) {
                int sg = s0 + wid * 32 + st * 16 + quad * 4 + r;
                float v = acc[ot][st][r] + bias;
                if (wi == 0)
                    gT[((size_t)n * CI + o) * NS + sg] = f2bf(v);
                else if (wi == 1)
                    theta[((size_t)n * NS + sg) * CI + o] = f2bf(v * KSCALE);
                else
                    phi[((size_t)n * NS + sg) * CI + o] = f2bf(v);
            }
        }
    }
}

// ---------------------------------------------------------------------------
// Kernel 2: flash attention partials.  grid(32 q-blocks, 4 s-splits, 4 n).
// Block = 4 waves, wave = 32 q rows (2 mfma tiles).  s-range 1024, 64/chunk.
// Writes unnormalized O + running (m, l) per row, merged by kernel 3.
// ---------------------------------------------------------------------------
__global__ __launch_bounds__(256, 2)
void attn_kernel(const unsigned short* __restrict__ theta,
                 const unsigned short* __restrict__ phi,
                 const unsigned short* __restrict__ gT,
                 float* __restrict__ Opart,
                 float* __restrict__ mbuf,
                 float* __restrict__ lbuf) {
    const int tid  = threadIdx.x;
    const int wid  = tid >> 6;
    const int lane = tid & 63;
    const int quad = lane >> 4;
    const int l15  = lane & 15;
    const int qb    = blockIdx.x;     // 0..31
    const int split = blockIdx.y;     // 0..3
    const int n     = blockIdx.z;     // 0..3
    const int qbase = qb * 128 + wid * 32;

    const unsigned short* thN = theta + (size_t)n * NS * CI;
    const unsigned short* phN = phi   + (size_t)n * NS * CI;
    const unsigned short* gN  = gT    + (size_t)n * CI * NS;

    __shared__ unsigned short Klds[64 * 136];        // [s][128c] pad->136
    __shared__ unsigned short Vlds[128 * 72];        // [c][64s]  pad->72
    __shared__ unsigned short Plds[4][2][16 * 72];   // per wave, per q-tile

    // preload Q fragments (invariant over s loop)
    bf16x8 qf[2][4];
#pragma unroll
    for (int qt = 0; qt < 2; qt++)
#pragma unroll
        for (int kc = 0; kc < 4; kc++)
            qf[qt][kc] = *(const bf16x8*)(thN + (size_t)(qbase + qt * 16 + l15) * CI + kc * 32 + quad * 8);

    f32x4 O[2][8];
#pragma unroll
    for (int qt = 0; qt < 2; qt++)
#pragma unroll
        for (int ct = 0; ct < 8; ct++) O[qt][ct] = (f32x4){0.f, 0.f, 0.f, 0.f};
    float mrun[2][4], lrun[2][4];
#pragma unroll
    for (int qt = 0; qt < 2; qt++)
#pragma unroll
        for (int r = 0; r < 4; r++) { mrun[qt][r] = -INFINITY; lrun[qt][r] = 0.f; }

    const int sbase0 = split * 1024;
    for (int ck = 0; ck < 16; ck++) {
        const int sb = sbase0 + ck * 64;
        __syncthreads();   // protect LDS from previous iteration's readers
        // stage K (phi rows): 1024 x 16B tasks, 4/thread
#pragma unroll
        for (int i = 0; i < 4; i++) {
            int t = tid + 256 * i;
            int s = t >> 4, cs = t & 15;
            *(uint4*)(&Klds[s * 136 + cs * 8]) =
                *(const uint4*)(phN + (size_t)(sb + s) * CI + cs * 8);
        }
        // stage V (gT rows): 1024 x 16B tasks, 4/thread
#pragma unroll
        for (int i = 0; i < 4; i++) {
            int t = tid + 256 * i;
            int c = t >> 3, ss = t & 7;
            *(uint4*)(&Vlds[c * 72 + ss * 8]) =
                *(const uint4*)(gN + (size_t)c * NS + sb + ss * 8);
        }
        __syncthreads();

        // QK^T : S[qt][st] (16q x 16s tiles)
        f32x4 S[2][4];
#pragma unroll
        for (int qt = 0; qt < 2; qt++)
#pragma unroll
            for (int st = 0; st < 4; st++) S[qt][st] = (f32x4){0.f, 0.f, 0.f, 0.f};
#pragma unroll
        for (int st = 0; st < 4; st++) {
#pragma unroll
            for (int kc = 0; kc < 4; kc++) {
                bf16x8 kf = *(const bf16x8*)(&Klds[(st * 16 + l15) * 136 + kc * 32 + quad * 8]);
#pragma unroll
                for (int qt = 0; qt < 2; qt++)
                    S[qt][st] = MFMA16(qf[qt][kc], kf, S[qt][st]);
            }
        }

        // online softmax per q-tile (rows live in quad: row = quad*4 + r)
#pragma unroll
        for (int qt = 0; qt < 2; qt++) {
            float nm[4], al[4];
#pragma unroll
            for (int r = 0; r < 4; r++) {
                float t = fmaxf(fmaxf(S[qt][0][r], S[qt][1][r]),
                                fmaxf(S[qt][2][r], S[qt][3][r]));
                t = fmaxf(t, __shfl_xor(t, 1));
                t = fmaxf(t, __shfl_xor(t, 2));
                t = fmaxf(t, __shfl_xor(t, 4));
                t = fmaxf(t, __shfl_xor(t, 8));
                nm[r] = fmaxf(mrun[qt][r], t);
                al[r] = EXP2F(mrun[qt][r] - nm[r]);   // 0 on first chunk
                mrun[qt][r] = nm[r];
            }
            float rs[4] = {0.f, 0.f, 0.f, 0.f};
#pragma unroll
            for (int st = 0; st < 4; st++) {
#pragma unroll
                for (int r = 0; r < 4; r++) {
                    float p = EXP2F(S[qt][st][r] - nm[r]);
                    rs[r] += p;
                    Plds[wid][qt][(quad * 4 + r) * 72 + st * 16 + l15] = f2bf(p);
                }
            }
#pragma unroll
            for (int r = 0; r < 4; r++) {
                float t = rs[r];
                t += __shfl_xor(t, 1);
                t += __shfl_xor(t, 2);
                t += __shfl_xor(t, 4);
                t += __shfl_xor(t, 8);
                lrun[qt][r] = lrun[qt][r] * al[r] + t;
            }
#pragma unroll
            for (int ct = 0; ct < 8; ct++)
#pragma unroll
                for (int r = 0; r < 4; r++) O[qt][ct][r] *= al[r];
        }

        // PV: O[qt][ct] += P . V   (LDS ops within a wave are in-order)
#pragma unroll
        for (int kc2 = 0; kc2 < 2; kc2++) {
            bf16x8 pa[2];
#pragma unroll
            for (int qt = 0; qt < 2; qt++)
                pa[qt] = *(const bf16x8*)(&Plds[wid][qt][l15 * 72 + kc2 * 32 + quad * 8]);
#pragma unroll
            for (int ct = 0; ct < 8; ct++) {
                bf16x8 vf = *(const bf16x8*)(&Vlds[(ct * 16 + l15) * 72 + kc2 * 32 + quad * 8]);
#pragma unroll
                for (int qt = 0; qt < 2; qt++)
                    O[qt][ct] = MFMA16(pa[qt], vf, O[qt][ct]);
            }
        }
    }

    // epilogue: unnormalized partials
    const size_t obase = ((size_t)split * NB + n) * NS * CI;
#pragma unroll
    for (int qt = 0; qt < 2; qt++) {
#pragma unroll
        for (int ct = 0; ct < 8; ct++) {
#pragma unroll
            for (int r = 0; r < 4; r++) {
                int q = qbase + qt * 16 + quad * 4 + r;
                Opart[obase + (size_t)q * CI + ct * 16 + l15] = O[qt][ct][r];
            }
        }
    }
    if (l15 == 0) {
#pragma unroll
        for (int qt = 0; qt < 2; qt++)
#pragma unroll
            for (int r = 0; r < 4; r++) {
                int q = qbase + qt * 16 + quad * 4 + r;
                int idx = split * (NB * NS) + n * NS + q;
                mbuf[idx] = mrun[qt][r];
                lbuf[idx] = lrun[qt][r];
            }
    }
}

// ---------------------------------------------------------------------------
// Kernel 3: merge 4 s-split partials -> y[n][s][c] (fp32).
// ---------------------------------------------------------------------------
__global__ void merge_kernel(const float* __restrict__ Opart,
                             const float* __restrict__ mbuf,
                             const float* __restrict__ lbuf,
                             float* __restrict__ y) {
    const int idx = blockIdx.x * 256 + threadIdx.x;   // 0..524287
    const int R   = idx >> 5;                          // row (n*4096+q)
    const int c4  = (idx & 31) * 4;
    const int T   = NB * NS;                           // 16384
    float m0 = mbuf[R], m1 = mbuf[T + R], m2 = mbuf[2 * T + R], m3 = mbuf[3 * T + R];
    float M = fmaxf(fmaxf(m0, m1), fmaxf(m2, m3));
    float e0 = EXP2F(m0 - M), e1 = EXP2F(m1 - M), e2 = EXP2F(m2 - M), e3 = EXP2F(m3 - M);
    float denom = e0 * lbuf[R] + e1 * lbuf[T + R] + e2 * lbuf[2 * T + R] + e3 * lbuf[3 * T + R];
    float rinv = 1.0f / denom;
    const size_t rowoff = (size_t)R * CI + c4;
    const size_t step = (size_t)T * CI;
    float4 o0 = *(const float4*)(Opart + rowoff);
    float4 o1 = *(const float4*)(Opart + step + rowoff);
    float4 o2 = *(const float4*)(Opart + 2 * step + rowoff);
    float4 o3 = *(const float4*)(Opart + 3 * step + rowoff);
    float4 r;
    r.x = (e0 * o0.x + e1 * o1.x + e2 * o2.x + e3 * o3.x) * rinv;
    r.y = (e0 * o0.y + e1 * o1.y + e2 * o2.y + e3 * o3.y) * rinv;
    r.z = (e0 * o0.z + e1 * o1.z + e2 * o2.z + e3 * o3.z) * rinv;
    r.w = (e0 * o0.w + e1 * o1.w + e2 * o2.w + e3 * o3.w) * rinv;
    *(float4*)(y + rowoff) = r;
}

// ---------------------------------------------------------------------------
// Kernel 4: output projection + residual.  grid(64 s-tiles, 4 n), 256 thr.
// out[n][o][s] = x[n][o][s] + b_out[o] + sum_c w_out[o][c] * y[n][s][c]
// ---------------------------------------------------------------------------
__global__ __launch_bounds__(256, 2)
void outproj_kernel(const float* __restrict__ x,
                    const float* __restrict__ w_out,
                    const float* __restrict__ b_out,
                    const float* __restrict__ y,
                    float* __restrict__ out) {
    const int tid  = threadIdx.x;
    const int wid  = tid >> 6;
    const int lane = tid & 63;
    const int quad = lane >> 4;
    const int l15  = lane & 15;
    const int n  = blockIdx.y;
    const int sw = blockIdx.x * 64 + wid * 16;

    const float* yN = y + ((size_t)n * NS + sw) * CI;
    f32x4 acc[16];
#pragma unroll
    for (int ot = 0; ot < 16; ot++) acc[ot] = (f32x4){0.f, 0.f, 0.f, 0.f};

#pragma unroll
    for (int kc = 0; kc < 4; kc++) {
        const float* yp = yN + (size_t)l15 * CI + kc * 32 + quad * 8;
        bf16x8 yb = cvt8(*(const float4*)yp, *(const float4*)(yp + 4));
#pragma unroll
        for (int ot = 0; ot < 16; ot++) {
            const float* wp = w_out + (size_t)(ot * 16 + l15) * CI + kc * 32 + quad * 8;
            bf16x8 wa = cvt8(*(const float4*)wp, *(const float4*)(wp + 4));
            acc[ot] = MFMA16(wa, yb, acc[ot]);
        }
    }
#pragma unroll
    for (int ot = 0; ot < 16; ot++) {
#pragma unroll
        for (int r = 0; r < 4; r++) {
            int o = ot * 16 + quad * 4 + r;
            size_t idx = ((size_t)n * CH + o) * NS + sw + l15;
            out[idx] = x[idx] + acc[ot][r] + b_out[o];
        }
    }
}

// ---------------------------------------------------------------------------
extern "C" void kernel_launch(void* const* d_in, const int* in_sizes, int n_in,
                              void* d_out, int out_size, void* d_ws, size_t ws_size,
                              hipStream_t stream) {
    const float* x     = (const float*)d_in[0];
    const float* w_g   = (const float*)d_in[1];
    const float* b_g   = (const float*)d_in[2];
    const float* w_th  = (const float*)d_in[3];
    const float* b_th  = (const float*)d_in[4];
    const float* w_ph  = (const float*)d_in[5];
    const float* b_ph  = (const float*)d_in[6];
    const float* w_out = (const float*)d_in[7];
    const float* b_out = (const float*)d_in[8];
    float* out = (float*)d_out;

    char* ws = (char*)d_ws;
    unsigned short* theta = (unsigned short*)(ws + 0);          //  4 MiB
    unsigned short* phi   = (unsigned short*)(ws + 4194304);    //  4 MiB
    unsigned short* gT    = (unsigned short*)(ws + 8388608);    //  4 MiB
    float* Opart = (float*)(ws + 12582912);                     // 32 MiB
    float* mbuf  = (float*)(ws + 46137344);                     // 256 KiB
    float* lbuf  = (float*)(ws + 46399488);                     // 256 KiB
    float* y     = (float*)(ws + 46661632);                     //  8 MiB

    proj_kernel<<<dim3(3, 32, NB), 256, 0, stream>>>(
        x, w_g, b_g, w_th, b_th, w_ph, b_ph, theta, phi, gT);
    attn_kernel<<<dim3(32, 4, NB), 256, 0, stream>>>(
        theta, phi, gT, Opart, mbuf, lbuf);
    merge_kernel<<<2048, 256, 0, stream>>>(Opart, mbuf, lbuf, y);
    outproj_kernel<<<dim3(64, NB), 256, 0, stream>>>(
        x, w_out, b_out, y, out);
}

// Round 2
// 184.690 us; speedup vs baseline: 1.2319x; 1.2319x over previous
//
#include <hip/hip_runtime.h>
#include <cmath>

typedef __attribute__((ext_vector_type(8))) short bf16x8;
typedef __attribute__((ext_vector_type(4))) float f32x4;

#define MFMA16(a,b,c) __builtin_amdgcn_mfma_f32_16x16x32_bf16((a),(b),(c),0,0,0)

#if __has_builtin(__builtin_amdgcn_exp2f)
#define EXP2F(x) __builtin_amdgcn_exp2f(x)
#else
#define EXP2F(x) exp2f(x)
#endif

// sqrt(128) * log2(e): folded into w_theta/b_theta at wcvt time.
#define KSCALE 16.3222312f

#define NB 4
#define CH 256
#define CI 128
#define NS 4096   // 64*64 spatial

__device__ __forceinline__ unsigned short f2bf(float f) {
    unsigned int u = __builtin_bit_cast(unsigned int, f);
    u += 0x7fffu + ((u >> 16) & 1u);           // RNE
    return (unsigned short)(u >> 16);
}
__device__ __forceinline__ unsigned int pk2(float lo, float hi) {
    return (unsigned int)f2bf(lo) | ((unsigned int)f2bf(hi) << 16);
}

// async global->LDS 16B per lane: LDS dest = uniform base + lane*16
__device__ __forceinline__ void gload16(void* lds, const void* g) {
    __builtin_amdgcn_global_load_lds(
        (const __attribute__((address_space(1))) unsigned int*)g,
        (__attribute__((address_space(3))) unsigned int*)lds,
        16, 0, 0);
}

// ---------------------------------------------------------------------------
// Kernel 0: one-time weight convert to bf16 (KSCALE folded into theta).
// wbf layout: [w_g | w_th*KSCALE | w_ph] (3*32768) + w_out (32768).
// bsc: [b_g | b_th*KSCALE | b_ph] (384 fp32).
// ---------------------------------------------------------------------------
__global__ void wcvt_kernel(const float* __restrict__ w_g, const float* __restrict__ w_th,
                            const float* __restrict__ w_ph, const float* __restrict__ w_out,
                            const float* __restrict__ b_g, const float* __restrict__ b_th,
                            const float* __restrict__ b_ph,
                            unsigned short* __restrict__ wbf, float* __restrict__ bsc) {
    int i = blockIdx.x * 256 + threadIdx.x;     // 0..131071
    float v;
    if (i < 32768)        v = w_g[i];
    else if (i < 65536)   v = w_th[i - 32768] * KSCALE;
    else if (i < 98304)   v = w_ph[i - 65536];
    else                  v = w_out[i - 98304];
    wbf[i] = f2bf(v);
    if (i < 128)          bsc[i] = b_g[i];
    else if (i < 256)     bsc[i] = b_th[i - 128] * KSCALE;
    else if (i < 384)     bsc[i] = b_ph[i - 256];
}

// ---------------------------------------------------------------------------
// Kernel 1: projections.  grid(3 weights, 32 s-tiles, 4 batches), 256 thr.
// ---------------------------------------------------------------------------
__global__ __launch_bounds__(256, 2)
void proj_kernel(const float* __restrict__ x,
                 const unsigned short* __restrict__ wbf, const float* __restrict__ bsc,
                 unsigned short* __restrict__ theta,
                 unsigned short* __restrict__ phi,
                 unsigned short* __restrict__ gT) {
    const int tid  = threadIdx.x;
    const int wid  = tid >> 6;
    const int lane = tid & 63;
    const int quad = lane >> 4;
    const int l15  = lane & 15;
    const int wi    = blockIdx.x;      // 0=g, 1=theta, 2=phi
    const int stile = blockIdx.y;      // 0..31 (128 s each)
    const int n     = blockIdx.z;
    const int s0    = stile * 128;

    const float* xN = x + (size_t)n * CH * NS;
    const unsigned short* W = wbf + (size_t)wi * 32768;
    const float* Bv = bsc + wi * 128;

    // [128 s][68 uint]  (64 used = 128 c as bf16 pairs, +4 pad -> 16B-aligned rows)
    __shared__ unsigned int xp[128 * 68];

    f32x4 acc[8][2];
#pragma unroll
    for (int ot = 0; ot < 8; ot++)
#pragma unroll
        for (int st = 0; st < 2; st++) acc[ot][st] = (f32x4){0.f, 0.f, 0.f, 0.f};

    for (int ch = 0; ch < 2; ch++) {       // two 128-channel halves
        __syncthreads();
#pragma unroll
        for (int i = 0; i < 8; i++) {
            int t  = tid + 256 * i;
            int cp = t >> 5;               // 0..63
            int s4 = t & 31;               // 0..31
            int c0 = ch * 128 + cp * 2;
            const float* p0 = xN + (size_t)c0 * NS + s0 + s4 * 4;
            float4 a = *(const float4*)p0;
            float4 b = *(const float4*)(p0 + NS);
            xp[(s4 * 4 + 0) * 68 + cp] = pk2(a.x, b.x);
            xp[(s4 * 4 + 1) * 68 + cp] = pk2(a.y, b.y);
            xp[(s4 * 4 + 2) * 68 + cp] = pk2(a.z, b.z);
            xp[(s4 * 4 + 3) * 68 + cp] = pk2(a.w, b.w);
        }
        __syncthreads();
#pragma unroll
        for (int kc = 0; kc < 4; kc++) {
            bf16x8 af[2];
#pragma unroll
            for (int st = 0; st < 2; st++) {
                int row = wid * 32 + st * 16 + l15;
                af[st] = *(const bf16x8*)(&xp[row * 68 + kc * 16 + quad * 4]);
            }
#pragma unroll
            for (int ot = 0; ot < 8; ot++) {
                bf16x8 bf = *(const bf16x8*)(W + (size_t)(ot * 16 + l15) * CH + ch * 128 + kc * 32 + quad * 8);
#pragma unroll
                for (int st = 0; st < 2; st++)
                    acc[ot][st] = MFMA16(af[st], bf, acc[ot][st]);
            }
        }
    }
    // epilogue: D row = s (quad*4+r), col = o (l15)
#pragma unroll
    for (int ot = 0; ot < 8; ot++) {
        int o = ot * 16 + l15;
        float bias = Bv[o];
#pragma unroll
        for (int st = 0; st < 2; st++) {
#pragma unroll
            for (int r = 0; r < 4; r++) {
                int sg = s0 + wid * 32 + st * 16 + quad * 4 + r;
                float v = acc[ot][st][r] + bias;
                if (wi == 0)
                    gT[((size_t)n * CI + o) * NS + sg] = f2bf(v);
                else if (wi == 1)
                    theta[((size_t)n * NS + sg) * CI + o] = f2bf(v);
                else
                    phi[((size_t)n * NS + sg) * CI + o] = f2bf(v);
            }
        }
    }
}

// ---------------------------------------------------------------------------
// Kernel 2: flash attention partials, S^T formulation.
// grid(32 q-blocks, 4 s-splits, 4 n).  Block = 4 waves, wave = 32 q rows.
// S^T = K.Q^T  (C-layout: row=s, col=q -> softmax stats in-lane + 2 shfls)
// O^T = V^T.P^T (P exchanged via per-wave swizzled LDS, vector ops only)
// K/V staged with async global_load_lds into XOR-swizzled unpadded LDS.
// ---------------------------------------------------------------------------
__global__ __launch_bounds__(256, 2)
void attn_kernel(const unsigned short* __restrict__ theta,
                 const unsigned short* __restrict__ phi,
                 const unsigned short* __restrict__ gT,
                 float* __restrict__ Opart,
                 float* __restrict__ mbuf,
                 float* __restrict__ lbuf) {
    const int tid  = threadIdx.x;
    const int wid  = tid >> 6;
    const int lane = tid & 63;
    const int quad = lane >> 4;
    const int l15  = lane & 15;
    const int qb    = blockIdx.x;     // 0..31
    const int split = blockIdx.y;     // 0..3
    const int n     = blockIdx.z;     // 0..3
    const int qbase = qb * 128 + wid * 32;

    const unsigned short* thN = theta + (size_t)n * NS * CI;
    const unsigned short* phN = phi   + (size_t)n * NS * CI;
    const unsigned short* gN  = gT    + (size_t)n * CI * NS;

    // K: [64 s][128 c] (16 chunks/row, chunk swizzle ^ (s&15))      16 KB
    // V: [128 c][64 s] ( 8 chunks/row, chunk swizzle ^ (c&7))       16 KB
    // P: per wave per qt: [16 q][64 s] (8 chunks, swizzle ^ (q&7))  16 KB
    __shared__ unsigned short smem[24576];
    unsigned short* Klds = smem;            // 8192 ush
    unsigned short* Vlds = smem + 8192;     // 8192 ush
    unsigned short* Plds = smem + 16384;    // 8192 ush

    // preload Q fragments: B-operand layout B[k=c][n=q]: lane holds
    // theta[q = l15][c = kc*32 + quad*8 + 0..7]
    bf16x8 qf[2][4];
#pragma unroll
    for (int qt = 0; qt < 2; qt++)
#pragma unroll
        for (int kc = 0; kc < 4; kc++)
            qf[qt][kc] = *(const bf16x8*)(thN + (size_t)(qbase + qt * 16 + l15) * CI + kc * 32 + quad * 8);

    f32x4 O[8][2];    // O^T tiles: [ct c-tile][qt]   (row=c, col=q)
#pragma unroll
    for (int ct = 0; ct < 8; ct++)
#pragma unroll
        for (int qt = 0; qt < 2; qt++) O[ct][qt] = (f32x4){0.f, 0.f, 0.f, 0.f};
    float mrun[2], lrun[2];
#pragma unroll
    for (int qt = 0; qt < 2; qt++) { mrun[qt] = -INFINITY; lrun[qt] = 0.f; }

    const int sbase0 = split * 1024;
    const int lh16 = lane >> 4, lm16 = lane & 15;   // K-staging lane split
    const int lh8  = lane >> 3, lm8  = lane & 7;    // V-staging lane split

    for (int ck = 0; ck < 16; ck++) {
        const int sb = sbase0 + ck * 64;
        __syncthreads();   // previous chunk's readers done
        // stage K: 16 segs of 4 rows (1KB each); lane -> (row lane>>4, chunk lane&15)
#pragma unroll
        for (int i = 0; i < 4; i++) {
            int seg = wid * 4 + i;
            int s   = seg * 4 + lh16;
            int j   = lm16 ^ (s & 15);
            gload16(Klds + seg * 512, phN + (size_t)(sb + s) * CI + j * 8);
        }
        // stage V: 16 segs of 8 rows; lane -> (row lane>>3, chunk lane&7)
#pragma unroll
        for (int i = 0; i < 4; i++) {
            int seg = wid * 4 + i;
            int c   = seg * 8 + lh8;
            int j   = lm8 ^ (c & 7);
            gload16(Vlds + seg * 512, gN + (size_t)c * NS + sb + j * 8);
        }
        __syncthreads();   // drains vmcnt before barrier (m97 pattern)

        // QK^T -> S^T[qt][st]: A = K rows (m=s), B = Q (n=q)
        f32x4 S[2][4];
#pragma unroll
        for (int qt = 0; qt < 2; qt++)
#pragma unroll
            for (int st = 0; st < 4; st++) S[qt][st] = (f32x4){0.f, 0.f, 0.f, 0.f};
#pragma unroll
        for (int st = 0; st < 4; st++) {
#pragma unroll
            for (int kc = 0; kc < 4; kc++) {
                int s = st * 16 + l15;
                bf16x8 kf = *(const bf16x8*)(Klds + s * 128 + ((kc * 4 + quad) ^ l15) * 8);
#pragma unroll
                for (int qt = 0; qt < 2; qt++)
                    S[qt][st] = MFMA16(kf, qf[qt][kc], S[qt][st]);
            }
        }

        // online softmax per qt: lane's col = q = l15; s spread in-lane + quads
#pragma unroll
        for (int qt = 0; qt < 2; qt++) {
            float t = S[qt][0][0];
#pragma unroll
            for (int st = 0; st < 4; st++)
#pragma unroll
                for (int r = 0; r < 4; r++) t = fmaxf(t, S[qt][st][r]);
            t = fmaxf(t, __shfl_xor(t, 16));
            t = fmaxf(t, __shfl_xor(t, 32));
            float nm = fmaxf(mrun[qt], t);
            float al = EXP2F(mrun[qt] - nm);
            mrun[qt] = nm;
            float rs = 0.f;
            unsigned int u[8];
#pragma unroll
            for (int st = 0; st < 4; st++) {
                float p0 = EXP2F(S[qt][st][0] - nm);
                float p1 = EXP2F(S[qt][st][1] - nm);
                float p2 = EXP2F(S[qt][st][2] - nm);
                float p3 = EXP2F(S[qt][st][3] - nm);
                rs += (p0 + p1) + (p2 + p3);
                u[st * 2]     = pk2(p0, p1);
                u[st * 2 + 1] = pk2(p2, p3);
            }
            rs += __shfl_xor(rs, 16);
            rs += __shfl_xor(rs, 32);
            lrun[qt] = lrun[qt] * al + rs;
            // store P: per st one b64 at [q=l15][chunk (st*2+(quad>>1)) ^ (l15&7)][(quad&1)*4]
            unsigned short* Pw = Plds + (wid * 2 + qt) * 1024 + l15 * 64 + (quad & 1) * 4;
#pragma unroll
            for (int st = 0; st < 4; st++) {
                int p = ((st * 2 + (quad >> 1)) ^ (l15 & 7)) * 8;
                *(uint2*)(Pw + p) = make_uint2(u[st * 2], u[st * 2 + 1]);
            }
            // rescale O^T (one alpha per lane: col q = l15)
#pragma unroll
            for (int ct = 0; ct < 8; ct++)
#pragma unroll
                for (int r = 0; r < 4; r++) O[ct][qt][r] *= al;
        }

        // PV: O^T += V^T . P^T   (A = V^T rows m=c, B = P^T: n=q, k=s)
#pragma unroll
        for (int kc2 = 0; kc2 < 2; kc2++) {
            bf16x8 pf[2];
#pragma unroll
            for (int qt = 0; qt < 2; qt++)
                pf[qt] = *(const bf16x8*)(Plds + (wid * 2 + qt) * 1024 + l15 * 64 + (((kc2 * 4 + quad) ^ (l15 & 7)) * 8));
#pragma unroll
            for (int ct = 0; ct < 8; ct++) {
                int c = ct * 16 + l15;
                bf16x8 vf = *(const bf16x8*)(Vlds + c * 64 + (((kc2 * 4 + quad) ^ (l15 & 7)) * 8));
#pragma unroll
                for (int qt = 0; qt < 2; qt++)
                    O[ct][qt] = MFMA16(vf, pf[qt], O[ct][qt]);
            }
        }
    }

    // epilogue: O^T (row=c,col=q) -> Opart[q][c] via per-wave LDS transpose
    __syncthreads();   // all waves done with K/V LDS
    float* tb = (float*)smem + wid * 2048;   // 8KB per wave
    const size_t obase = ((size_t)split * NB + n) * NS * CI;
#pragma unroll
    for (int qt = 0; qt < 2; qt++) {
#pragma unroll
        for (int ct = 0; ct < 8; ct++) {
            int p = (ct * 4 + quad) ^ l15;   // 32 chunks/row, swizzle key = row q
            *(f32x4*)(tb + l15 * 128 + p * 4) = O[ct][qt];
        }
#pragma unroll
        for (int i = 0; i < 8; i++) {
            int flat = i * 64 + lane;
            int row = flat >> 5, jj = flat & 31;
            int p2 = jj ^ row;
            f32x4 v = *(const f32x4*)(tb + row * 128 + p2 * 4);
            int q = qbase + qt * 16 + row;
            *(f32x4*)(Opart + obase + (size_t)q * CI + jj * 4) = v;
        }
    }
    if (quad == 0) {
#pragma unroll
        for (int qt = 0; qt < 2; qt++) {
            int q = qbase + qt * 16 + l15;
            int idx = split * (NB * NS) + n * NS + q;
            mbuf[idx] = mrun[qt];
            lbuf[idx] = lrun[qt];
        }
    }
}

// ---------------------------------------------------------------------------
// Kernel 3: merge 4 s-split partials -> ybf[n][s][c] (bf16).
// ---------------------------------------------------------------------------
__global__ void merge_kernel(const float* __restrict__ Opart,
                             const float* __restrict__ mbuf,
                             const float* __restrict__ lbuf,
                             unsigned short* __restrict__ ybf) {
    const int idx = blockIdx.x * 256 + threadIdx.x;   // 0..524287
    const int R   = idx >> 5;                          // row (n*4096+q)
    const int c4  = (idx & 31) * 4;
    const int T   = NB * NS;                           // 16384
    float m0 = mbuf[R], m1 = mbuf[T + R], m2 = mbuf[2 * T + R], m3 = mbuf[3 * T + R];
    float M = fmaxf(fmaxf(m0, m1), fmaxf(m2, m3));
    float e0 = EXP2F(m0 - M), e1 = EXP2F(m1 - M), e2 = EXP2F(m2 - M), e3 = EXP2F(m3 - M);
    float denom = e0 * lbuf[R] + e1 * lbuf[T + R] + e2 * lbuf[2 * T + R] + e3 * lbuf[3 * T + R];
    float rinv = 1.0f / denom;
    const size_t rowoff = (size_t)R * CI + c4;
    const size_t step = (size_t)T * CI;
    float4 o0 = *(const float4*)(Opart + rowoff);
    float4 o1 = *(const float4*)(Opart + step + rowoff);
    float4 o2 = *(const float4*)(Opart + 2 * step + rowoff);
    float4 o3 = *(const float4*)(Opart + 3 * step + rowoff);
    float rx = (e0 * o0.x + e1 * o1.x + e2 * o2.x + e3 * o3.x) * rinv;
    float ry = (e0 * o0.y + e1 * o1.y + e2 * o2.y + e3 * o3.y) * rinv;
    float rz = (e0 * o0.z + e1 * o1.z + e2 * o2.z + e3 * o3.z) * rinv;
    float rw = (e0 * o0.w + e1 * o1.w + e2 * o2.w + e3 * o3.w) * rinv;
    *(uint2*)(ybf + rowoff) = make_uint2(pk2(rx, ry), pk2(rz, rw));
}

// ---------------------------------------------------------------------------
// Kernel 4: output projection + residual.  grid(64 s-tiles, 4 n), 256 thr.
// ---------------------------------------------------------------------------
__global__ __launch_bounds__(256, 2)
void outproj_kernel(const float* __restrict__ x,
                    const unsigned short* __restrict__ wbf,
                    const float* __restrict__ b_out,
                    const unsigned short* __restrict__ ybf,
                    float* __restrict__ out) {
    const int tid  = threadIdx.x;
    const int wid  = tid >> 6;
    const int lane = tid & 63;
    const int quad = lane >> 4;
    const int l15  = lane & 15;
    const int n  = blockIdx.y;
    const int sw = blockIdx.x * 64 + wid * 16;

    const unsigned short* wob = wbf + 3 * 32768;
    const unsigned short* yN  = ybf + ((size_t)n * NS + sw) * CI;
    f32x4 acc[16];
#pragma unroll
    for (int ot = 0; ot < 16; ot++) acc[ot] = (f32x4){0.f, 0.f, 0.f, 0.f};

#pragma unroll
    for (int kc = 0; kc < 4; kc++) {
        bf16x8 yb = *(const bf16x8*)(yN + (size_t)l15 * CI + kc * 32 + quad * 8);
#pragma unroll
        for (int ot = 0; ot < 16; ot++) {
            bf16x8 wa = *(const bf16x8*)(wob + (size_t)(ot * 16 + l15) * CI + kc * 32 + quad * 8);
            acc[ot] = MFMA16(wa, yb, acc[ot]);
        }
    }
#pragma unroll
    for (int ot = 0; ot < 16; ot++) {
#pragma unroll
        for (int r = 0; r < 4; r++) {
            int o = ot * 16 + quad * 4 + r;
            size_t idx = ((size_t)n * CH + o) * NS + sw + l15;
            out[idx] = x[idx] + acc[ot][r] + b_out[o];
        }
    }
}

// ---------------------------------------------------------------------------
extern "C" void kernel_launch(void* const* d_in, const int* in_sizes, int n_in,
                              void* d_out, int out_size, void* d_ws, size_t ws_size,
                              hipStream_t stream) {
    const float* x     = (const float*)d_in[0];
    const float* w_g   = (const float*)d_in[1];
    const float* b_g   = (const float*)d_in[2];
    const float* w_th  = (const float*)d_in[3];
    const float* b_th  = (const float*)d_in[4];
    const float* w_ph  = (const float*)d_in[5];
    const float* b_ph  = (const float*)d_in[6];
    const float* w_out = (const float*)d_in[7];
    const float* b_out = (const float*)d_in[8];
    float* out = (float*)d_out;

    char* ws = (char*)d_ws;
    unsigned short* theta = (unsigned short*)(ws + 0);          //  4 MiB
    unsigned short* phi   = (unsigned short*)(ws + 4194304);    //  4 MiB
    unsigned short* gT    = (unsigned short*)(ws + 8388608);    //  4 MiB
    float* Opart = (float*)(ws + 12582912);                     // 32 MiB
    float* mbuf  = (float*)(ws + 46137344);                     // 256 KiB
    float* lbuf  = (float*)(ws + 46399488);                     // 256 KiB
    unsigned short* ybf = (unsigned short*)(ws + 46661632);     //  4 MiB
    unsigned short* wbf = (unsigned short*)(ws + 50855936);     // 256 KiB
    float* bsc   = (float*)(ws + 51118080);                     //  1.5 KiB

    wcvt_kernel<<<512, 256, 0, stream>>>(w_g, w_th, w_ph, w_out, b_g, b_th, b_ph, wbf, bsc);
    proj_kernel<<<dim3(3, 32, NB), 256, 0, stream>>>(x, wbf, bsc, theta, phi, gT);
    attn_kernel<<<dim3(32, 4, NB), 256, 0, stream>>>(theta, phi, gT, Opart, mbuf, lbuf);
    merge_kernel<<<2048, 256, 0, stream>>>(Opart, mbuf, lbuf, ybf);
    outproj_kernel<<<dim3(64, NB), 256, 0, stream>>>(x, wbf, b_out, ybf, out);
}